// Round 1
// baseline (5431.805 us; speedup 1.0000x reference)
//
#include <hip/hip_runtime.h>

#define IN_CH 128
#define HID 16

// ---------------- degree / normalization ----------------

__global__ void deg_init_kernel(int* __restrict__ deg, int n) {
    int i = blockIdx.x * blockDim.x + threadIdx.x;
    if (i < n) deg[i] = 1;  // self-loop contributes 1
}

__global__ void deg_count_kernel(const int* __restrict__ col, int* __restrict__ deg, int e) {
    int i = blockIdx.x * blockDim.x + threadIdx.x;
    if (i < e) atomicAdd(&deg[col[i]], 1);
}

__global__ void dinv_kernel(const int* __restrict__ deg, float* __restrict__ dinv, int n) {
    int i = blockIdx.x * blockDim.x + threadIdx.x;
    if (i < n) dinv[i] = 1.0f / sqrtf((float)deg[i]);
}

// ---------------- layer 1 dense: h = x @ W1  (N x 128 -> N x 16) ----------------

__global__ __launch_bounds__(256) void gemm1_kernel(
    const float* __restrict__ x, const float* __restrict__ W1,
    float* __restrict__ h, int n) {
    __shared__ float sx[16][IN_CH + 4];   // +4 pad: (4r+k)%32 distinct for r=0..3 -> conflict-free
    __shared__ float sw[IN_CH][HID];
    int t = threadIdx.x;
    for (int i = t; i < IN_CH * HID; i += 256) sw[i / HID][i % HID] = W1[i];
    int row0 = blockIdx.x * 16;
    for (int i = t; i < 16 * IN_CH; i += 256) {
        int r = i >> 7, k = i & 127;
        int gr = row0 + r;
        sx[r][k] = (gr < n) ? x[(size_t)gr * IN_CH + k] : 0.0f;
    }
    __syncthreads();
    int r = t >> 4, c = t & 15;
    float acc = 0.0f;
#pragma unroll
    for (int k = 0; k < IN_CH; ++k) acc += sx[r][k] * sw[k][c];
    int gr = row0 + r;
    if (gr < n) h[(size_t)gr * HID + c] = acc;
}

// ---------------- aggregation ----------------
// out[i] = dinv[i]^2 * h[i]   (self-loop term), one thread per float4
__global__ void selfloop_kernel(const float* __restrict__ h, const float* __restrict__ dinv,
                                float* __restrict__ out, int n) {
    int i = blockIdx.x * blockDim.x + threadIdx.x;
    int node = i >> 2;
    if (node >= n) return;
    float d = dinv[node];
    float s = d * d;
    float4 v = ((const float4*)h)[i];
    v.x *= s; v.y *= s; v.z *= s; v.w *= s;
    ((float4*)out)[i] = v;
}

// out[col[e]] += dinv[row]*dinv[col] * h[row[e]], one thread per edge
__global__ void edge_agg_kernel(const int* __restrict__ row, const int* __restrict__ col,
                                const float* __restrict__ dinv, const float* __restrict__ h,
                                float* __restrict__ out, int e) {
    int i = blockIdx.x * blockDim.x + threadIdx.x;
    if (i >= e) return;
    int r = row[i], c = col[i];
    float norm = dinv[r] * dinv[c];
    const float4* hr = (const float4*)(h + (size_t)r * HID);
    float* oc = out + (size_t)c * HID;
#pragma unroll
    for (int q = 0; q < 4; ++q) {
        float4 v = hr[q];
        atomicAdd(oc + q * 4 + 0, v.x * norm);
        atomicAdd(oc + q * 4 + 1, v.y * norm);
        atomicAdd(oc + q * 4 + 2, v.z * norm);
        atomicAdd(oc + q * 4 + 3, v.w * norm);
    }
}

// ---------------- layer 2 dense: h2 = relu(agg1 + b1) @ W2  (16x16) ----------------

__global__ __launch_bounds__(256) void gemm2_kernel(
    const float* __restrict__ agg, const float* __restrict__ b1,
    const float* __restrict__ W2, float* __restrict__ h2, int n) {
    __shared__ float sw[HID * HID];
    __shared__ float sb[HID];
    int t = threadIdx.x;
    if (t < HID * HID) sw[t] = W2[t];
    if (t < HID) sb[t] = b1[t];
    __syncthreads();
    int i = blockIdx.x * 256 + t;
    if (i >= n) return;
    float a[HID];
    const float4* ap = (const float4*)(agg + (size_t)i * HID);
#pragma unroll
    for (int q = 0; q < 4; ++q) {
        float4 v = ap[q];
        a[4 * q + 0] = v.x; a[4 * q + 1] = v.y; a[4 * q + 2] = v.z; a[4 * q + 3] = v.w;
    }
#pragma unroll
    for (int k = 0; k < HID; ++k) a[k] = fmaxf(a[k] + sb[k], 0.0f);
    float o[HID];
#pragma unroll
    for (int c = 0; c < HID; ++c) {
        float acc = 0.0f;
#pragma unroll
        for (int k = 0; k < HID; ++k) acc += a[k] * sw[k * HID + c];
        o[c] = acc;
    }
    float4* op = (float4*)(h2 + (size_t)i * HID);
#pragma unroll
    for (int q = 0; q < 4; ++q) {
        float4 v;
        v.x = o[4 * q + 0]; v.y = o[4 * q + 1]; v.z = o[4 * q + 2]; v.w = o[4 * q + 3];
        op[q] = v;
    }
}

// ---------------- head: out = relu(agg2 + b2) @ Wl + bl ----------------

__global__ __launch_bounds__(256) void final_kernel(
    const float* __restrict__ agg, const float* __restrict__ b2,
    const float* __restrict__ Wl, const float* __restrict__ bl,
    float* __restrict__ out, int n) {
    __shared__ float sw[HID];
    __shared__ float sb[HID];
    __shared__ float sbl;
    int t = threadIdx.x;
    if (t < HID) { sw[t] = Wl[t]; sb[t] = b2[t]; }
    if (t == 0) sbl = bl[0];
    __syncthreads();
    int i = blockIdx.x * 256 + t;
    if (i >= n) return;
    const float4* ap = (const float4*)(agg + (size_t)i * HID);
    float acc = sbl;
#pragma unroll
    for (int q = 0; q < 4; ++q) {
        float4 v = ap[q];
        acc += fmaxf(v.x + sb[4 * q + 0], 0.0f) * sw[4 * q + 0];
        acc += fmaxf(v.y + sb[4 * q + 1], 0.0f) * sw[4 * q + 1];
        acc += fmaxf(v.z + sb[4 * q + 2], 0.0f) * sw[4 * q + 2];
        acc += fmaxf(v.w + sb[4 * q + 3], 0.0f) * sw[4 * q + 3];
    }
    out[i] = acc;
}

extern "C" void kernel_launch(void* const* d_in, const int* in_sizes, int n_in,
                              void* d_out, int out_size, void* d_ws, size_t ws_size,
                              hipStream_t stream) {
    const float* x  = (const float*)d_in[0];
    const int*   ei = (const int*)d_in[1];
    const float* W1 = (const float*)d_in[2];
    const float* b1 = (const float*)d_in[3];
    const float* W2 = (const float*)d_in[4];
    const float* b2 = (const float*)d_in[5];
    const float* Wl = (const float*)d_in[6];
    const float* bl = (const float*)d_in[7];

    int n = in_sizes[0] / IN_CH;
    int e = in_sizes[1] / 2;
    const int* row = ei;        // sources
    const int* col = ei + e;    // targets

    // workspace layout (ping-pong the two N x 16 buffers)
    char* ws = (char*)d_ws;
    size_t off = 0;
    auto alloc = [&](size_t bytes) -> void* {
        void* p = ws + off;
        off = (off + bytes + 255) & ~(size_t)255;
        return p;
    };
    int*   deg  = (int*)alloc((size_t)n * sizeof(int));
    float* dinv = (float*)alloc((size_t)n * sizeof(float));
    float* bufA = (float*)alloc((size_t)n * HID * sizeof(float));
    float* bufB = (float*)alloc((size_t)n * HID * sizeof(float));

    const int tb = 256;
    dim3 blk(tb);
    dim3 gN((n + tb - 1) / tb);
    dim3 gN4((n * 4 + tb - 1) / tb);
    dim3 gE((e + tb - 1) / tb);
    dim3 gG((n + 15) / 16);

    hipLaunchKernelGGL(deg_init_kernel,  gN,  blk, 0, stream, deg, n);
    hipLaunchKernelGGL(deg_count_kernel, gE,  blk, 0, stream, col, deg, e);
    hipLaunchKernelGGL(dinv_kernel,      gN,  blk, 0, stream, deg, dinv, n);

    // layer 1
    hipLaunchKernelGGL(gemm1_kernel,     gG,  blk, 0, stream, x, W1, bufA, n);
    hipLaunchKernelGGL(selfloop_kernel,  gN4, blk, 0, stream, bufA, dinv, bufB, n);
    hipLaunchKernelGGL(edge_agg_kernel,  gE,  blk, 0, stream, row, col, dinv, bufA, bufB, e);

    // layer 2 (bias+relu of layer-1 agg fused into gemm2)
    hipLaunchKernelGGL(gemm2_kernel,     gN,  blk, 0, stream, bufB, b1, W2, bufA, n);
    hipLaunchKernelGGL(selfloop_kernel,  gN4, blk, 0, stream, bufA, dinv, bufB, n);
    hipLaunchKernelGGL(edge_agg_kernel,  gE,  blk, 0, stream, row, col, dinv, bufA, bufB, e);

    // head (bias+relu of layer-2 agg fused)
    hipLaunchKernelGGL(final_kernel,     gN,  blk, 0, stream, bufB, b2, Wl, bl, (float*)d_out, n);
}

// Round 2
// 447.123 us; speedup vs baseline: 12.1484x; 12.1484x over previous
//
#include <hip/hip_runtime.h>

#define IN_CH 128
#define HID 16
#define SCAN_B 256

// ---------------- degree / normalization ----------------

__global__ void deg_init_kernel(int* __restrict__ deg, int n) {
    int i = blockIdx.x * blockDim.x + threadIdx.x;
    if (i < n) deg[i] = 1;  // self-loop contributes 1
}

__global__ void deg_count_kernel(const int* __restrict__ col, int* __restrict__ deg, int e) {
    int i = blockIdx.x * blockDim.x + threadIdx.x;
    if (i < e) atomicAdd(&deg[col[i]], 1);
}

// ---------------- exclusive scan of edge-only in-degree (deg-1) ----------------

__global__ __launch_bounds__(SCAN_B) void scan1_kernel(
    const int* __restrict__ deg, int* __restrict__ row_ptr, int* __restrict__ bsum, int n) {
    __shared__ int s[SCAN_B];
    int t = threadIdx.x;
    int i = blockIdx.x * SCAN_B + t;
    int v = (i < n) ? (deg[i] - 1) : 0;   // edge-only count (exclude self-loop)
    s[t] = v;
    __syncthreads();
    for (int off = 1; off < SCAN_B; off <<= 1) {
        int add = (t >= off) ? s[t - off] : 0;
        __syncthreads();
        s[t] += add;
        __syncthreads();
    }
    if (i < n) row_ptr[i] = s[t] - v;                  // exclusive within block
    if (t == SCAN_B - 1) bsum[blockIdx.x] = s[t];      // block total
}

__global__ __launch_bounds__(512) void scan2_kernel(int* __restrict__ bsum, int nb) {
    __shared__ int s[512];
    int t = threadIdx.x;
    int v = (t < nb) ? bsum[t] : 0;
    s[t] = v;
    __syncthreads();
    for (int off = 1; off < 512; off <<= 1) {
        int add = (t >= off) ? s[t - off] : 0;
        __syncthreads();
        s[t] += add;
        __syncthreads();
    }
    if (t < nb) bsum[t] = s[t] - v;  // exclusive
}

// finalize: global row_ptr, init cursor, compute dinv; thread 0 writes row_ptr[n]=e
__global__ void scan3_kernel(int* __restrict__ row_ptr, const int* __restrict__ bsum,
                             int* __restrict__ cursor, const int* __restrict__ deg,
                             float* __restrict__ dinv, int n, int e) {
    int i = blockIdx.x * blockDim.x + threadIdx.x;
    if (i == 0) row_ptr[n] = e;
    if (i >= n) return;
    int rp = row_ptr[i] + bsum[i >> 8];   // blockDim==SCAN_B==256
    row_ptr[i] = rp;
    cursor[i] = rp;
    dinv[i] = rsqrtf((float)deg[i]);
}

// ---------------- CSR bucket fill: pk[pos] = {src, dinv[src]*dinv[dst]} ----------------

__global__ void fill_kernel(const int* __restrict__ row, const int* __restrict__ col,
                            const float* __restrict__ dinv, int* __restrict__ cursor,
                            int2* __restrict__ pk, int e) {
    int i = blockIdx.x * blockDim.x + threadIdx.x;
    if (i >= e) return;
    int r = row[i], c = col[i];
    int pos = atomicAdd(&cursor[c], 1);
    float w = dinv[r] * dinv[c];
    pk[pos] = make_int2(r, __float_as_int(w));
}

// ---------------- layer 1 dense: h = x @ W1  (N x 128 -> N x 16) ----------------

__global__ __launch_bounds__(256) void gemm1_kernel(
    const float* __restrict__ x, const float* __restrict__ W1,
    float* __restrict__ h, int n) {
    __shared__ float sx[16][IN_CH + 4];
    __shared__ float sw[IN_CH][HID];
    int t = threadIdx.x;
    for (int i = t; i < IN_CH * HID; i += 256) sw[i / HID][i % HID] = W1[i];
    int row0 = blockIdx.x * 16;
    for (int i = t; i < 16 * IN_CH; i += 256) {
        int r = i >> 7, k = i & 127;
        int gr = row0 + r;
        sx[r][k] = (gr < n) ? x[(size_t)gr * IN_CH + k] : 0.0f;
    }
    __syncthreads();
    int r = t >> 4, c = t & 15;
    float acc = 0.0f;
#pragma unroll
    for (int k = 0; k < IN_CH; ++k) acc += sx[r][k] * sw[k][c];
    int gr = row0 + r;
    if (gr < n) h[(size_t)gr * HID + c] = acc;
}

// ---------------- gather aggregation: out[g,c] = dinv[g]^2 h[g,c] + sum_j w_j h[src_j,c] ----------------

__global__ __launch_bounds__(256) void agg_kernel(
    const float* __restrict__ h, const int* __restrict__ row_ptr,
    const int2* __restrict__ pk, const float* __restrict__ dinv,
    float* __restrict__ out, int n) {
    int g = blockIdx.x * 16 + (threadIdx.x >> 4);
    int c = threadIdx.x & 15;
    if (g >= n) return;
    float d = dinv[g];
    float acc = d * d * h[(size_t)g * HID + c];
    int beg = row_ptr[g], end = row_ptr[g + 1];
    int j = beg;
    for (; j + 1 < end; j += 2) {
        int2 e0 = pk[j];
        int2 e1 = pk[j + 1];
        acc += __int_as_float(e0.y) * h[(size_t)e0.x * HID + c];
        acc += __int_as_float(e1.y) * h[(size_t)e1.x * HID + c];
    }
    if (j < end) {
        int2 e0 = pk[j];
        acc += __int_as_float(e0.y) * h[(size_t)e0.x * HID + c];
    }
    out[(size_t)g * HID + c] = acc;
}

// ---------------- (fallback) atomic scatter path, round-1 proven ----------------

__global__ void dinv_kernel(const int* __restrict__ deg, float* __restrict__ dinv, int n) {
    int i = blockIdx.x * blockDim.x + threadIdx.x;
    if (i < n) dinv[i] = 1.0f / sqrtf((float)deg[i]);
}

__global__ void selfloop_kernel(const float* __restrict__ h, const float* __restrict__ dinv,
                                float* __restrict__ out, int n) {
    int i = blockIdx.x * blockDim.x + threadIdx.x;
    int node = i >> 2;
    if (node >= n) return;
    float d = dinv[node];
    float s = d * d;
    float4 v = ((const float4*)h)[i];
    v.x *= s; v.y *= s; v.z *= s; v.w *= s;
    ((float4*)out)[i] = v;
}

__global__ void edge_agg_kernel(const int* __restrict__ row, const int* __restrict__ col,
                                const float* __restrict__ dinv, const float* __restrict__ h,
                                float* __restrict__ out, int e) {
    int i = blockIdx.x * blockDim.x + threadIdx.x;
    if (i >= e) return;
    int r = row[i], c = col[i];
    float norm = dinv[r] * dinv[c];
    const float4* hr = (const float4*)(h + (size_t)r * HID);
    float* oc = out + (size_t)c * HID;
#pragma unroll
    for (int q = 0; q < 4; ++q) {
        float4 v = hr[q];
        atomicAdd(oc + q * 4 + 0, v.x * norm);
        atomicAdd(oc + q * 4 + 1, v.y * norm);
        atomicAdd(oc + q * 4 + 2, v.z * norm);
        atomicAdd(oc + q * 4 + 3, v.w * norm);
    }
}

// ---------------- layer 2 dense: h2 = relu(agg1 + b1) @ W2  (16x16) ----------------

__global__ __launch_bounds__(256) void gemm2_kernel(
    const float* __restrict__ agg, const float* __restrict__ b1,
    const float* __restrict__ W2, float* __restrict__ h2, int n) {
    __shared__ float sw[HID * HID];
    __shared__ float sb[HID];
    int t = threadIdx.x;
    if (t < HID * HID) sw[t] = W2[t];
    if (t < HID) sb[t] = b1[t];
    __syncthreads();
    int i = blockIdx.x * 256 + t;
    if (i >= n) return;
    float a[HID];
    const float4* ap = (const float4*)(agg + (size_t)i * HID);
#pragma unroll
    for (int q = 0; q < 4; ++q) {
        float4 v = ap[q];
        a[4 * q + 0] = v.x; a[4 * q + 1] = v.y; a[4 * q + 2] = v.z; a[4 * q + 3] = v.w;
    }
#pragma unroll
    for (int k = 0; k < HID; ++k) a[k] = fmaxf(a[k] + sb[k], 0.0f);
    float o[HID];
#pragma unroll
    for (int c = 0; c < HID; ++c) {
        float acc = 0.0f;
#pragma unroll
        for (int k = 0; k < HID; ++k) acc += a[k] * sw[k * HID + c];
        o[c] = acc;
    }
    float4* op = (float4*)(h2 + (size_t)i * HID);
#pragma unroll
    for (int q = 0; q < 4; ++q) {
        float4 v;
        v.x = o[4 * q + 0]; v.y = o[4 * q + 1]; v.z = o[4 * q + 2]; v.w = o[4 * q + 3];
        op[q] = v;
    }
}

// ---------------- head: out = relu(agg2 + b2) @ Wl + bl ----------------

__global__ __launch_bounds__(256) void final_kernel(
    const float* __restrict__ agg, const float* __restrict__ b2,
    const float* __restrict__ Wl, const float* __restrict__ bl,
    float* __restrict__ out, int n) {
    __shared__ float sw[HID];
    __shared__ float sb[HID];
    __shared__ float sbl;
    int t = threadIdx.x;
    if (t < HID) { sw[t] = Wl[t]; sb[t] = b2[t]; }
    if (t == 0) sbl = bl[0];
    __syncthreads();
    int i = blockIdx.x * 256 + t;
    if (i >= n) return;
    const float4* ap = (const float4*)(agg + (size_t)i * HID);
    float acc = sbl;
#pragma unroll
    for (int q = 0; q < 4; ++q) {
        float4 v = ap[q];
        acc += fmaxf(v.x + sb[4 * q + 0], 0.0f) * sw[4 * q + 0];
        acc += fmaxf(v.y + sb[4 * q + 1], 0.0f) * sw[4 * q + 1];
        acc += fmaxf(v.z + sb[4 * q + 2], 0.0f) * sw[4 * q + 2];
        acc += fmaxf(v.w + sb[4 * q + 3], 0.0f) * sw[4 * q + 3];
    }
    out[i] = acc;
}

extern "C" void kernel_launch(void* const* d_in, const int* in_sizes, int n_in,
                              void* d_out, int out_size, void* d_ws, size_t ws_size,
                              hipStream_t stream) {
    const float* x  = (const float*)d_in[0];
    const int*   ei = (const int*)d_in[1];
    const float* W1 = (const float*)d_in[2];
    const float* b1 = (const float*)d_in[3];
    const float* W2 = (const float*)d_in[4];
    const float* b2 = (const float*)d_in[5];
    const float* Wl = (const float*)d_in[6];
    const float* bl = (const float*)d_in[7];

    int n = in_sizes[0] / IN_CH;
    int e = in_sizes[1] / 2;
    const int* row = ei;        // sources
    const int* col = ei + e;    // targets

    char* ws = (char*)d_ws;
    size_t off = 0;
    auto alloc = [&](size_t bytes) -> void* {
        void* p = ws + off;
        off = (off + bytes + 255) & ~(size_t)255;
        return p;
    };

    const int tb = 256;
    dim3 blk(tb);
    dim3 gN((n + tb - 1) / tb);
    dim3 gE((e + tb - 1) / tb);
    dim3 gG((n + 15) / 16);

    int nblk = (n + SCAN_B - 1) / SCAN_B;   // 391 for n=100000; must be <= 512

    // CSR-path workspace
    size_t need = 0;
    {
        size_t o2 = 0;
        auto sim = [&](size_t b) { o2 = (o2 + b + 255) & ~(size_t)255; };
        sim((size_t)n * 4);            // deg
        sim((size_t)n * 4);            // dinv
        sim(((size_t)n + 1) * 4);      // row_ptr
        sim((size_t)n * 4);            // cursor
        sim((size_t)nblk * 4);         // bsum
        sim((size_t)e * 8);            // pk
        sim((size_t)n * HID * 4);      // bufA
        sim((size_t)n * HID * 4);      // bufB
        need = o2;
    }

    if (ws_size >= need && nblk <= 512) {
        int*   deg     = (int*)alloc((size_t)n * 4);
        float* dinv    = (float*)alloc((size_t)n * 4);
        int*   row_ptr = (int*)alloc(((size_t)n + 1) * 4);
        int*   cursor  = (int*)alloc((size_t)n * 4);
        int*   bsum    = (int*)alloc((size_t)nblk * 4);
        int2*  pk      = (int2*)alloc((size_t)e * 8);
        float* bufA    = (float*)alloc((size_t)n * HID * 4);
        float* bufB    = (float*)alloc((size_t)n * HID * 4);

        hipLaunchKernelGGL(deg_init_kernel,  gN, blk, 0, stream, deg, n);
        hipLaunchKernelGGL(deg_count_kernel, gE, blk, 0, stream, col, deg, e);
        hipLaunchKernelGGL(scan1_kernel, dim3(nblk), dim3(SCAN_B), 0, stream, deg, row_ptr, bsum, n);
        hipLaunchKernelGGL(scan2_kernel, dim3(1), dim3(512), 0, stream, bsum, nblk);
        hipLaunchKernelGGL(scan3_kernel, gN, blk, 0, stream, row_ptr, bsum, cursor, deg, dinv, n, e);
        hipLaunchKernelGGL(fill_kernel,  gE, blk, 0, stream, row, col, dinv, cursor, pk, e);

        // layer 1
        hipLaunchKernelGGL(gemm1_kernel, gG, blk, 0, stream, x, W1, bufA, n);
        hipLaunchKernelGGL(agg_kernel,   gG, blk, 0, stream, bufA, row_ptr, pk, dinv, bufB, n);
        // layer 2
        hipLaunchKernelGGL(gemm2_kernel, gN, blk, 0, stream, bufB, b1, W2, bufA, n);
        hipLaunchKernelGGL(agg_kernel,   gG, blk, 0, stream, bufA, row_ptr, pk, dinv, bufB, n);
        // head
        hipLaunchKernelGGL(final_kernel, gN, blk, 0, stream, bufB, b2, Wl, bl, (float*)d_out, n);
    } else {
        // fallback: round-1 atomic path
        int*   deg  = (int*)alloc((size_t)n * 4);
        float* dinv = (float*)alloc((size_t)n * 4);
        float* bufA = (float*)alloc((size_t)n * HID * 4);
        float* bufB = (float*)alloc((size_t)n * HID * 4);
        dim3 gN4((n * 4 + tb - 1) / tb);

        hipLaunchKernelGGL(deg_init_kernel,  gN, blk, 0, stream, deg, n);
        hipLaunchKernelGGL(deg_count_kernel, gE, blk, 0, stream, col, deg, e);
        hipLaunchKernelGGL(dinv_kernel,      gN, blk, 0, stream, deg, dinv, n);
        hipLaunchKernelGGL(gemm1_kernel,     gG, blk, 0, stream, x, W1, bufA, n);
        hipLaunchKernelGGL(selfloop_kernel,  gN4, blk, 0, stream, bufA, dinv, bufB, n);
        hipLaunchKernelGGL(edge_agg_kernel,  gE, blk, 0, stream, row, col, dinv, bufA, bufB, e);
        hipLaunchKernelGGL(gemm2_kernel,     gN, blk, 0, stream, bufB, b1, W2, bufA, n);
        hipLaunchKernelGGL(selfloop_kernel,  gN4, blk, 0, stream, bufA, dinv, bufB, n);
        hipLaunchKernelGGL(edge_agg_kernel,  gE, blk, 0, stream, row, col, dinv, bufA, bufB, e);
        hipLaunchKernelGGL(final_kernel,     gN, blk, 0, stream, bufB, b2, Wl, bl, (float*)d_out, n);
    }
}

// Round 3
// 421.118 us; speedup vs baseline: 12.8985x; 1.0618x over previous
//
#include <hip/hip_runtime.h>

#define IN_CH 128
#define HID 16
#define SCAN_B 256
#define NXCD 8

// ---------------- degree count (edge-only; self-loop added in scan3) ----------------

__global__ void deg_count_kernel(const int* __restrict__ col, int* __restrict__ deg, int e) {
    int i = blockIdx.x * blockDim.x + threadIdx.x;
    if (i < e) atomicAdd(&deg[col[i]], 1);
}

// ---------------- exclusive scan of edge-only in-degree ----------------

__global__ __launch_bounds__(SCAN_B) void scan1_kernel(
    const int* __restrict__ deg, int* __restrict__ row_ptr, int* __restrict__ bsum, int n) {
    __shared__ int s[SCAN_B];
    int t = threadIdx.x;
    int i = blockIdx.x * SCAN_B + t;
    int v = (i < n) ? deg[i] : 0;
    s[t] = v;
    __syncthreads();
    for (int off = 1; off < SCAN_B; off <<= 1) {
        int add = (t >= off) ? s[t - off] : 0;
        __syncthreads();
        s[t] += add;
        __syncthreads();
    }
    if (i < n) row_ptr[i] = s[t] - v;                  // exclusive within block
    if (t == SCAN_B - 1) bsum[blockIdx.x] = s[t];      // block total
}

__global__ __launch_bounds__(512) void scan2_kernel(int* __restrict__ bsum, int nb) {
    __shared__ int s[512];
    int t = threadIdx.x;
    int v = (t < nb) ? bsum[t] : 0;
    s[t] = v;
    __syncthreads();
    for (int off = 1; off < 512; off <<= 1) {
        int add = (t >= off) ? s[t - off] : 0;
        __syncthreads();
        s[t] += add;
        __syncthreads();
    }
    if (t < nb) bsum[t] = s[t] - v;  // exclusive
}

__global__ void scan3_kernel(int* __restrict__ row_ptr, const int* __restrict__ bsum,
                             int* __restrict__ cursor, const int* __restrict__ deg,
                             float* __restrict__ dinv, int n, int e) {
    int i = blockIdx.x * blockDim.x + threadIdx.x;
    if (i == 0) row_ptr[n] = e;
    if (i >= n) return;
    int rp = row_ptr[i] + bsum[i >> 8];   // blockDim==SCAN_B==256
    row_ptr[i] = rp;
    cursor[i] = rp;
    dinv[i] = rsqrtf((float)(deg[i] + 1));   // +1 self-loop
}

// ---------------- XCD-partitioned CSR bucket fill ----------------
// Block b: k = b%8 (presumed XCD via round-robin dispatch), chunk j = b/8.
// XCD k only writes pk positions for destinations in [k*rsize, (k+1)*rsize)
// -> its 3.2 MB pk window stays resident in its own 4 MB L2, so each 64B
// line is written whole and evicted once (kills the 8x sector amplification).

__global__ __launch_bounds__(256) void fill_kernel(
    const int* __restrict__ row, const int* __restrict__ col,
    const float* __restrict__ dinv, int* __restrict__ cursor,
    int2* __restrict__ pk, int e, int rsize) {
    int k = blockIdx.x & (NXCD - 1);
    int j = blockIdx.x >> 3;
    int lo = k * rsize, hi = lo + rsize;
    int base = j * 1024 + (threadIdx.x << 2);
    if (base >= e) return;
    int4 c4 = make_int4(-1, -1, -1, -1);
    if (base + 3 < e) {
        c4 = *(const int4*)(col + base);
    } else {
        c4.x = col[base];
        if (base + 1 < e) c4.y = col[base + 1];
        if (base + 2 < e) c4.z = col[base + 2];
    }
#pragma unroll
    for (int q = 0; q < 4; ++q) {
        int c = (q == 0) ? c4.x : (q == 1) ? c4.y : (q == 2) ? c4.z : c4.w;
        if (c >= lo && c < hi) {
            int r = row[base + q];
            float w = dinv[r] * dinv[c];
            int pos = atomicAdd(&cursor[c], 1);
            pk[pos] = make_int2(r, __float_as_int(w));
        }
    }
}

// ---------------- layer 1 dense: h = x @ W1  (N x 128 -> N x 16) ----------------

__global__ __launch_bounds__(256) void gemm1_kernel(
    const float* __restrict__ x, const float* __restrict__ W1,
    float* __restrict__ h, int n) {
    __shared__ float sx[16][IN_CH + 4];
    __shared__ float sw[IN_CH][HID];
    int t = threadIdx.x;
    // W1: 2048 floats = 512 float4
#pragma unroll
    for (int i = t; i < 512; i += 256) {
        float4 v = ((const float4*)W1)[i];
        int rr = i >> 2, cc = (i & 3) << 2;
        sw[rr][cc] = v.x; sw[rr][cc + 1] = v.y; sw[rr][cc + 2] = v.z; sw[rr][cc + 3] = v.w;
    }
    int row0 = blockIdx.x * 16;
#pragma unroll
    for (int i = t; i < 512; i += 256) {
        int r = i >> 5, k4 = (i & 31) << 2;
        int gr = row0 + r;
        float4 v = make_float4(0.f, 0.f, 0.f, 0.f);
        if (gr < n) v = *(const float4*)(x + (size_t)gr * IN_CH + k4);
        *(float4*)&sx[r][k4] = v;
    }
    __syncthreads();
    int r = t >> 4, c = t & 15;
    float acc = 0.0f;
#pragma unroll
    for (int k = 0; k < IN_CH; ++k) acc += sx[r][k] * sw[k][c];
    int gr = row0 + r;
    if (gr < n) h[(size_t)gr * HID + c] = acc;
}

// ---------------- aggregation (gather), 4 lanes/node, float4/lane ----------------
// acc = dinv^2 * h[node] + sum_j w_j * h[src_j]
// agg1: epilogue = h2 = relu(acc + b1) @ W2   (shuffle-rotated 4x4 blocks)
// agg2: epilogue = out = relu(acc + b2) . Wl + bl

__global__ __launch_bounds__(256) void agg1_kernel(
    const float* __restrict__ h, const int* __restrict__ row_ptr,
    const int2* __restrict__ pk, const float* __restrict__ dinv,
    const float* __restrict__ b1, const float* __restrict__ W2,
    float* __restrict__ h2, int n) {
    int t = threadIdx.x;
    int node = blockIdx.x * 64 + (t >> 2);
    int sub = t & 3;
    if (node >= n) return;   // whole 4-lane group exits together
    const float4* h4 = (const float4*)h;
    float d = dinv[node];
    float s = d * d;
    float4 self = h4[(size_t)node * 4 + sub];
    float cx = s * self.x, cy = s * self.y, cz = s * self.z, cw = s * self.w;
    int beg = row_ptr[node], end = row_ptr[node + 1];
    int j = beg;
    for (; j + 1 < end; j += 2) {
        int2 e0 = pk[j];
        int2 e1 = pk[j + 1];
        float w0 = __int_as_float(e0.y), w1 = __int_as_float(e1.y);
        float4 v0 = h4[(size_t)e0.x * 4 + sub];
        float4 v1 = h4[(size_t)e1.x * 4 + sub];
        cx += w0 * v0.x + w1 * v1.x;
        cy += w0 * v0.y + w1 * v1.y;
        cz += w0 * v0.z + w1 * v1.z;
        cw += w0 * v0.w + w1 * v1.w;
    }
    if (j < end) {
        int2 e0 = pk[j];
        float w0 = __int_as_float(e0.y);
        float4 v0 = h4[(size_t)e0.x * 4 + sub];
        cx += w0 * v0.x; cy += w0 * v0.y; cz += w0 * v0.z; cw += w0 * v0.w;
    }
    // epilogue: relu(acc + b1) @ W2, gathering all 16 channels via 4-lane xor rotation
    float4 b1v = *(const float4*)(b1 + (sub << 2));
    float ax = fmaxf(cx + b1v.x, 0.f);
    float ay = fmaxf(cy + b1v.y, 0.f);
    float az = fmaxf(cz + b1v.z, 0.f);
    float aw = fmaxf(cw + b1v.w, 0.f);
    float ox = 0.f, oy = 0.f, oz = 0.f, ow = 0.f;
#pragma unroll
    for (int r = 0; r < 4; ++r) {
        float fx = __shfl_xor(ax, r);
        float fy = __shfl_xor(ay, r);
        float fz = __shfl_xor(az, r);
        float fw = __shfl_xor(aw, r);
        int kb = (sub ^ r) << 2;                       // input-channel block held by partner lane
        const float* wp = W2 + kb * HID + (sub << 2);  // rows kb..kb+3, cols 4*sub..
        float4 w0 = *(const float4*)(wp);
        float4 w1 = *(const float4*)(wp + HID);
        float4 w2 = *(const float4*)(wp + 2 * HID);
        float4 w3 = *(const float4*)(wp + 3 * HID);
        ox += fx * w0.x + fy * w1.x + fz * w2.x + fw * w3.x;
        oy += fx * w0.y + fy * w1.y + fz * w2.y + fw * w3.y;
        oz += fx * w0.z + fy * w1.z + fz * w2.z + fw * w3.z;
        ow += fx * w0.w + fy * w1.w + fz * w2.w + fw * w3.w;
    }
    float4 o; o.x = ox; o.y = oy; o.z = oz; o.w = ow;
    ((float4*)h2)[(size_t)node * 4 + sub] = o;
}

__global__ __launch_bounds__(256) void agg2_kernel(
    const float* __restrict__ h, const int* __restrict__ row_ptr,
    const int2* __restrict__ pk, const float* __restrict__ dinv,
    const float* __restrict__ b2, const float* __restrict__ Wl,
    const float* __restrict__ bl, float* __restrict__ out, int n) {
    int t = threadIdx.x;
    int node = blockIdx.x * 64 + (t >> 2);
    int sub = t & 3;
    if (node >= n) return;
    const float4* h4 = (const float4*)h;
    float d = dinv[node];
    float s = d * d;
    float4 self = h4[(size_t)node * 4 + sub];
    float cx = s * self.x, cy = s * self.y, cz = s * self.z, cw = s * self.w;
    int beg = row_ptr[node], end = row_ptr[node + 1];
    int j = beg;
    for (; j + 1 < end; j += 2) {
        int2 e0 = pk[j];
        int2 e1 = pk[j + 1];
        float w0 = __int_as_float(e0.y), w1 = __int_as_float(e1.y);
        float4 v0 = h4[(size_t)e0.x * 4 + sub];
        float4 v1 = h4[(size_t)e1.x * 4 + sub];
        cx += w0 * v0.x + w1 * v1.x;
        cy += w0 * v0.y + w1 * v1.y;
        cz += w0 * v0.z + w1 * v1.z;
        cw += w0 * v0.w + w1 * v1.w;
    }
    if (j < end) {
        int2 e0 = pk[j];
        float w0 = __int_as_float(e0.y);
        float4 v0 = h4[(size_t)e0.x * 4 + sub];
        cx += w0 * v0.x; cy += w0 * v0.y; cz += w0 * v0.z; cw += w0 * v0.w;
    }
    // epilogue: relu(acc + b2) . Wl, reduce across the 4 lanes, + bl
    float4 b2v = *(const float4*)(b2 + (sub << 2));
    float4 wlv = *(const float4*)(Wl + (sub << 2));
    float p = fmaxf(cx + b2v.x, 0.f) * wlv.x
            + fmaxf(cy + b2v.y, 0.f) * wlv.y
            + fmaxf(cz + b2v.z, 0.f) * wlv.z
            + fmaxf(cw + b2v.w, 0.f) * wlv.w;
    p += __shfl_xor(p, 1);
    p += __shfl_xor(p, 2);
    if (sub == 0) out[node] = p + bl[0];
}

extern "C" void kernel_launch(void* const* d_in, const int* in_sizes, int n_in,
                              void* d_out, int out_size, void* d_ws, size_t ws_size,
                              hipStream_t stream) {
    const float* x  = (const float*)d_in[0];
    const int*   ei = (const int*)d_in[1];
    const float* W1 = (const float*)d_in[2];
    const float* b1 = (const float*)d_in[3];
    const float* W2 = (const float*)d_in[4];
    const float* b2 = (const float*)d_in[5];
    const float* Wl = (const float*)d_in[6];
    const float* bl = (const float*)d_in[7];

    int n = in_sizes[0] / IN_CH;
    int e = in_sizes[1] / 2;
    const int* row = ei;        // sources
    const int* col = ei + e;    // targets

    char* ws = (char*)d_ws;
    size_t off = 0;
    auto alloc = [&](size_t bytes) -> void* {
        void* p = ws + off;
        off = (off + bytes + 255) & ~(size_t)255;
        return p;
    };

    int nblk = (n + SCAN_B - 1) / SCAN_B;   // 391 for n=100000 (<= 512)

    int*   deg     = (int*)alloc((size_t)n * 4);
    float* dinv    = (float*)alloc((size_t)n * 4);
    int*   row_ptr = (int*)alloc(((size_t)n + 1) * 4);
    int*   cursor  = (int*)alloc((size_t)n * 4);
    int*   bsum    = (int*)alloc((size_t)nblk * 4);
    int2*  pk      = (int2*)alloc((size_t)e * 8);
    float* bufA    = (float*)alloc((size_t)n * HID * 4);
    float* bufB    = (float*)alloc((size_t)n * HID * 4);

    const int tb = 256;
    dim3 blk(tb);
    dim3 gN((n + tb - 1) / tb);
    dim3 gE((e + tb - 1) / tb);
    dim3 gG((n + 15) / 16);
    dim3 gA((n + 63) / 64);

    int rsize  = (n + NXCD - 1) / NXCD;
    int nchunk = (e + 1023) / 1024;
    dim3 gF(nchunk * NXCD);

    hipMemsetAsync(deg, 0, (size_t)n * 4, stream);
    hipLaunchKernelGGL(deg_count_kernel, gE, blk, 0, stream, col, deg, e);
    hipLaunchKernelGGL(scan1_kernel, dim3(nblk), dim3(SCAN_B), 0, stream, deg, row_ptr, bsum, n);
    hipLaunchKernelGGL(scan2_kernel, dim3(1), dim3(512), 0, stream, bsum, nblk);
    hipLaunchKernelGGL(scan3_kernel, gN, blk, 0, stream, row_ptr, bsum, cursor, deg, dinv, n, e);
    hipLaunchKernelGGL(fill_kernel,  gF, blk, 0, stream, row, col, dinv, cursor, pk, e, rsize);

    hipLaunchKernelGGL(gemm1_kernel, gG, blk, 0, stream, x, W1, bufA, n);
    hipLaunchKernelGGL(agg1_kernel,  gA, blk, 0, stream, bufA, row_ptr, pk, dinv, b1, W2, bufB, n);
    hipLaunchKernelGGL(agg2_kernel,  gA, blk, 0, stream, bufB, row_ptr, pk, dinv, b2, Wl, bl, (float*)d_out, n);
}

// Round 4
// 180.341 us; speedup vs baseline: 30.1196x; 2.3351x over previous
//
#include <hip/hip_runtime.h>

#define IN_CH 128
#define HID 16
#define SHIFT 8            // bucket = dst >> 8  (256 nodes per bucket)
#define CA 16384           // edges per block in pass-A kernels
#define SCAN_B 512
#define MAXNB 512

// ============ pass A1: per-block per-bucket histogram ============
// histT[b * nba + j] = count of edges in block j with dst-bucket b
__global__ __launch_bounds__(256) void histA_kernel(
    const int* __restrict__ col, int* __restrict__ histT, int e, int NB, int nba) {
    __shared__ int hist[MAXNB];
    int j = blockIdx.x, t = threadIdx.x;
    for (int b = t; b < NB; b += 256) hist[b] = 0;
    __syncthreads();
    int e4 = e >> 2;
    const int4* c4p = (const int4*)col;
#pragma unroll
    for (int k = 0; k < CA / 1024; ++k) {
        int i4 = j * (CA / 4) + k * 256 + t;
        if (i4 < e4) {
            int4 c = c4p[i4];
            atomicAdd(&hist[c.x >> SHIFT], 1);
            atomicAdd(&hist[c.y >> SHIFT], 1);
            atomicAdd(&hist[c.z >> SHIFT], 1);
            atomicAdd(&hist[c.w >> SHIFT], 1);
        }
    }
    if (j == gridDim.x - 1) {  // scalar tail if e % 4 != 0
        for (int i = (e & ~3) + t; i < e; i += 256) atomicAdd(&hist[col[i] >> SHIFT], 1);
    }
    __syncthreads();
    for (int b = t; b < NB; b += 256) histT[b * nba + j] = hist[b];
}

// ============ generic 2-level exclusive scan ============

__global__ __launch_bounds__(SCAN_B) void scan1_kernel(
    const int* __restrict__ in, int* __restrict__ out, int* __restrict__ bsum, int m) {
    __shared__ int s[SCAN_B];
    int t = threadIdx.x;
    int i = blockIdx.x * SCAN_B + t;
    int v = (i < m) ? in[i] : 0;
    s[t] = v;
    __syncthreads();
    for (int off = 1; off < SCAN_B; off <<= 1) {
        int a = (t >= off) ? s[t - off] : 0;
        __syncthreads();
        s[t] += a;
        __syncthreads();
    }
    if (i < m) out[i] = s[t] - v;
    if (t == SCAN_B - 1) bsum[blockIdx.x] = s[t];
}

__global__ __launch_bounds__(SCAN_B) void scan2_kernel(int* __restrict__ bsum, int nb) {
    __shared__ int s[SCAN_B];
    int t = threadIdx.x;
    int v = (t < nb) ? bsum[t] : 0;
    s[t] = v;
    __syncthreads();
    for (int off = 1; off < SCAN_B; off <<= 1) {
        int a = (t >= off) ? s[t - off] : 0;
        __syncthreads();
        s[t] += a;
        __syncthreads();
    }
    if (t < nb) bsum[t] = s[t] - v;
}

__global__ void scanadd_kernel(int* __restrict__ data, const int* __restrict__ bsum, int m) {
    int i = blockIdx.x * blockDim.x + threadIdx.x;
    if (i < m) data[i] += bsum[i >> 9];   // SCAN_B == 512
}

// ============ pass A3: scatter edges into bucket runs (coalesced-ish) ============
// tmp[pos] = (src << 8) | (dst & 255); runs per (block,bucket) are contiguous.
__global__ __launch_bounds__(256) void scatterA_kernel(
    const int* __restrict__ row, const int* __restrict__ col,
    const int* __restrict__ histTs, int* __restrict__ tmp, int e, int NB, int nba) {
    __shared__ int cur[MAXNB];
    int j = blockIdx.x, t = threadIdx.x;
    for (int b = t; b < NB; b += 256) cur[b] = histTs[b * nba + j];
    __syncthreads();
    int e4 = e >> 2;
    const int4* c4p = (const int4*)col;
    const int4* r4p = (const int4*)row;
#pragma unroll
    for (int k = 0; k < CA / 1024; ++k) {
        int i4 = j * (CA / 4) + k * 256 + t;
        if (i4 < e4) {
            int4 c = c4p[i4];
            int4 r = r4p[i4];
            int pos;
            pos = atomicAdd(&cur[c.x >> SHIFT], 1); tmp[pos] = (r.x << 8) | (c.x & 255);
            pos = atomicAdd(&cur[c.y >> SHIFT], 1); tmp[pos] = (r.y << 8) | (c.y & 255);
            pos = atomicAdd(&cur[c.z >> SHIFT], 1); tmp[pos] = (r.z << 8) | (c.z & 255);
            pos = atomicAdd(&cur[c.w >> SHIFT], 1); tmp[pos] = (r.w << 8) | (c.w & 255);
        }
    }
    if (j == gridDim.x - 1) {
        for (int i = (e & ~3) + t; i < e; i += 256) {
            int c = col[i], r = row[i];
            int pos = atomicAdd(&cur[c >> SHIFT], 1);
            tmp[pos] = (r << 8) | (c & 255);
        }
    }
}

// ============ pass B: per-bucket CSR finalize ============
// Builds row_ptr, dinv, and pk (src-only) for its 256-node bucket; all LDS
// cursors, pk writes land in a 32 KB L2-resident window.
__global__ __launch_bounds__(256) void bucketB_kernel(
    const int* __restrict__ tmp, const int* __restrict__ histTs,
    int* __restrict__ row_ptr, float* __restrict__ dinv, int* __restrict__ pk,
    int n, int e, int NB, int nba) {
    __shared__ int hcnt[256];
    __shared__ int scn[256];
    __shared__ int cur[256];
    int b = blockIdx.x, t = threadIdx.x;
    int bs = histTs[b * nba];
    int be = (b + 1 < NB) ? histTs[(b + 1) * nba] : e;
    hcnt[t] = 0;
    __syncthreads();
    for (int i = bs + t; i < be; i += 256) atomicAdd(&hcnt[tmp[i] & 255], 1);
    __syncthreads();
    int v = hcnt[t];
    scn[t] = v;
    __syncthreads();
    for (int off = 1; off < 256; off <<= 1) {
        int a = (t >= off) ? scn[t - off] : 0;
        __syncthreads();
        scn[t] += a;
        __syncthreads();
    }
    int excl = scn[t] - v;
    int node = (b << SHIFT) + t;
    if (node < n) {
        row_ptr[node] = bs + excl;
        dinv[node] = rsqrtf((float)(v + 1));   // +1 self-loop
    }
    cur[t] = bs + excl;
    if (b == NB - 1 && t == 0) row_ptr[n] = e;
    __syncthreads();
    for (int i = bs + t; i < be; i += 256) {
        int u = tmp[i];
        int pos = atomicAdd(&cur[u & 255], 1);
        pk[pos] = u >> 8;
    }
}

// ============ layer 1 dense: hs = dinv * (x @ W1) ============

__global__ __launch_bounds__(256) void gemm1_kernel(
    const float* __restrict__ x, const float* __restrict__ W1,
    const float* __restrict__ dinv, float* __restrict__ hs, int n) {
    __shared__ float sx[16][IN_CH + 4];
    __shared__ float sw[IN_CH][HID];
    int t = threadIdx.x;
#pragma unroll
    for (int i = t; i < 512; i += 256) {
        float4 v = ((const float4*)W1)[i];
        int rr = i >> 2, cc = (i & 3) << 2;
        sw[rr][cc] = v.x; sw[rr][cc + 1] = v.y; sw[rr][cc + 2] = v.z; sw[rr][cc + 3] = v.w;
    }
    int row0 = blockIdx.x * 16;
#pragma unroll
    for (int i = t; i < 512; i += 256) {
        int r = i >> 5, k4 = (i & 31) << 2;
        int gr = row0 + r;
        float4 v = make_float4(0.f, 0.f, 0.f, 0.f);
        if (gr < n) v = *(const float4*)(x + (size_t)gr * IN_CH + k4);
        *(float4*)&sx[r][k4] = v;
    }
    __syncthreads();
    int r = t >> 4, c = t & 15;
    float acc = 0.0f;
#pragma unroll
    for (int k = 0; k < IN_CH; ++k) acc += sx[r][k] * sw[k][c];
    int gr = row0 + r;
    if (gr < n) hs[(size_t)gr * HID + c] = acc * dinv[gr];
}

// ============ aggregation (weightless gather), 4 lanes/node ============
// acc = hs[g] + sum_src hs[src];  conv_out = dinv[g]*acc (+bias later)
// agg1 epilogue: hs2 = dinv[g] * ( relu(dinv[g]*acc + b1) @ W2 )
// agg2 epilogue: out = relu(dinv[g]*acc + b2) . Wl + bl

__global__ __launch_bounds__(256) void agg1_kernel(
    const float* __restrict__ hs, const int* __restrict__ row_ptr,
    const int* __restrict__ pk, const float* __restrict__ dinv,
    const float* __restrict__ b1, const float* __restrict__ W2,
    float* __restrict__ hs2, int n) {
    int t = threadIdx.x;
    int node = blockIdx.x * 64 + (t >> 2);
    int sub = t & 3;
    if (node >= n) return;   // whole 4-lane group exits together
    const float4* h4 = (const float4*)hs;
    float4 self = h4[(size_t)node * 4 + sub];
    float cx = self.x, cy = self.y, cz = self.z, cw = self.w;
    int beg = row_ptr[node], end = row_ptr[node + 1];
    int j = beg;
    for (; j + 3 < end; j += 4) {
        int s0 = pk[j], s1 = pk[j + 1], s2 = pk[j + 2], s3 = pk[j + 3];
        float4 v0 = h4[(size_t)s0 * 4 + sub];
        float4 v1 = h4[(size_t)s1 * 4 + sub];
        float4 v2 = h4[(size_t)s2 * 4 + sub];
        float4 v3 = h4[(size_t)s3 * 4 + sub];
        cx += v0.x + v1.x + v2.x + v3.x;
        cy += v0.y + v1.y + v2.y + v3.y;
        cz += v0.z + v1.z + v2.z + v3.z;
        cw += v0.w + v1.w + v2.w + v3.w;
    }
    for (; j < end; ++j) {
        float4 v0 = h4[(size_t)pk[j] * 4 + sub];
        cx += v0.x; cy += v0.y; cz += v0.z; cw += v0.w;
    }
    float dg = dinv[node];
    float4 b1v = *(const float4*)(b1 + (sub << 2));
    float ax = fmaxf(dg * cx + b1v.x, 0.f);
    float ay = fmaxf(dg * cy + b1v.y, 0.f);
    float az = fmaxf(dg * cz + b1v.z, 0.f);
    float aw = fmaxf(dg * cw + b1v.w, 0.f);
    float ox = 0.f, oy = 0.f, oz = 0.f, ow = 0.f;
#pragma unroll
    for (int r = 0; r < 4; ++r) {
        float fx = __shfl_xor(ax, r);
        float fy = __shfl_xor(ay, r);
        float fz = __shfl_xor(az, r);
        float fw = __shfl_xor(aw, r);
        int kb = (sub ^ r) << 2;
        const float* wp = W2 + kb * HID + (sub << 2);
        float4 w0 = *(const float4*)(wp);
        float4 w1 = *(const float4*)(wp + HID);
        float4 w2 = *(const float4*)(wp + 2 * HID);
        float4 w3 = *(const float4*)(wp + 3 * HID);
        ox += fx * w0.x + fy * w1.x + fz * w2.x + fw * w3.x;
        oy += fx * w0.y + fy * w1.y + fz * w2.y + fw * w3.y;
        oz += fx * w0.z + fy * w1.z + fz * w2.z + fw * w3.z;
        ow += fx * w0.w + fy * w1.w + fz * w2.w + fw * w3.w;
    }
    float4 o; o.x = dg * ox; o.y = dg * oy; o.z = dg * oz; o.w = dg * ow;
    ((float4*)hs2)[(size_t)node * 4 + sub] = o;
}

__global__ __launch_bounds__(256) void agg2_kernel(
    const float* __restrict__ hs2, const int* __restrict__ row_ptr,
    const int* __restrict__ pk, const float* __restrict__ dinv,
    const float* __restrict__ b2, const float* __restrict__ Wl,
    const float* __restrict__ bl, float* __restrict__ out, int n) {
    int t = threadIdx.x;
    int node = blockIdx.x * 64 + (t >> 2);
    int sub = t & 3;
    if (node >= n) return;
    const float4* h4 = (const float4*)hs2;
    float4 self = h4[(size_t)node * 4 + sub];
    float cx = self.x, cy = self.y, cz = self.z, cw = self.w;
    int beg = row_ptr[node], end = row_ptr[node + 1];
    int j = beg;
    for (; j + 3 < end; j += 4) {
        int s0 = pk[j], s1 = pk[j + 1], s2 = pk[j + 2], s3 = pk[j + 3];
        float4 v0 = h4[(size_t)s0 * 4 + sub];
        float4 v1 = h4[(size_t)s1 * 4 + sub];
        float4 v2 = h4[(size_t)s2 * 4 + sub];
        float4 v3 = h4[(size_t)s3 * 4 + sub];
        cx += v0.x + v1.x + v2.x + v3.x;
        cy += v0.y + v1.y + v2.y + v3.y;
        cz += v0.z + v1.z + v2.z + v3.z;
        cw += v0.w + v1.w + v2.w + v3.w;
    }
    for (; j < end; ++j) {
        float4 v0 = h4[(size_t)pk[j] * 4 + sub];
        cx += v0.x; cy += v0.y; cz += v0.z; cw += v0.w;
    }
    float dg = dinv[node];
    float4 b2v = *(const float4*)(b2 + (sub << 2));
    float4 wlv = *(const float4*)(Wl + (sub << 2));
    float p = fmaxf(dg * cx + b2v.x, 0.f) * wlv.x
            + fmaxf(dg * cy + b2v.y, 0.f) * wlv.y
            + fmaxf(dg * cz + b2v.z, 0.f) * wlv.z
            + fmaxf(dg * cw + b2v.w, 0.f) * wlv.w;
    p += __shfl_xor(p, 1);
    p += __shfl_xor(p, 2);
    if (sub == 0) out[node] = p + bl[0];
}

extern "C" void kernel_launch(void* const* d_in, const int* in_sizes, int n_in,
                              void* d_out, int out_size, void* d_ws, size_t ws_size,
                              hipStream_t stream) {
    const float* x  = (const float*)d_in[0];
    const int*   ei = (const int*)d_in[1];
    const float* W1 = (const float*)d_in[2];
    const float* b1 = (const float*)d_in[3];
    const float* W2 = (const float*)d_in[4];
    const float* b2 = (const float*)d_in[5];
    const float* Wl = (const float*)d_in[6];
    const float* bl = (const float*)d_in[7];

    int n = in_sizes[0] / IN_CH;
    int e = in_sizes[1] / 2;
    const int* row = ei;        // sources
    const int* col = ei + e;    // targets

    int NB  = (n + 255) >> SHIFT;          // 391 dst-buckets of 256 nodes
    int nba = (e + CA - 1) / CA;           // 196 pass-A blocks
    int m   = NB * nba;                    // 76,636 scan elements
    int nsb = (m + SCAN_B - 1) / SCAN_B;   // 150 (<= 512)

    char* ws = (char*)d_ws;
    size_t off = 0;
    auto alloc = [&](size_t bytes) -> void* {
        void* p = ws + off;
        off = (off + bytes + 255) & ~(size_t)255;
        return p;
    };

    int*   histT  = (int*)alloc((size_t)m * 4);
    int*   histTs = (int*)alloc((size_t)m * 4);
    int*   bsum   = (int*)alloc((size_t)nsb * 4);
    int*   tmp    = (int*)alloc((size_t)e * 4);
    int*   pk     = (int*)alloc((size_t)e * 4);
    int*   row_ptr= (int*)alloc(((size_t)n + 1) * 4);
    float* dinv   = (float*)alloc((size_t)n * 4);
    float* bufA   = (float*)alloc((size_t)n * HID * 4);
    float* bufB   = (float*)alloc((size_t)n * HID * 4);

    dim3 blk(256);
    dim3 gG((n + 15) / 16);
    dim3 gA((n + 63) / 64);

    // build CSR (sorted-by-destination) without any global fp or scattered-8B writes
    hipLaunchKernelGGL(histA_kernel,    dim3(nba), blk, 0, stream, col, histT, e, NB, nba);
    hipLaunchKernelGGL(scan1_kernel,    dim3(nsb), dim3(SCAN_B), 0, stream, histT, histTs, bsum, m);
    hipLaunchKernelGGL(scan2_kernel,    dim3(1),   dim3(SCAN_B), 0, stream, bsum, nsb);
    hipLaunchKernelGGL(scanadd_kernel,  dim3((m + 255) / 256), blk, 0, stream, histTs, bsum, m);
    hipLaunchKernelGGL(scatterA_kernel, dim3(nba), blk, 0, stream, row, col, histTs, tmp, e, NB, nba);
    hipLaunchKernelGGL(bucketB_kernel,  dim3(NB),  blk, 0, stream, tmp, histTs, row_ptr, dinv, pk, n, e, NB, nba);

    // network
    hipLaunchKernelGGL(gemm1_kernel, gG, blk, 0, stream, x, W1, dinv, bufA, n);
    hipLaunchKernelGGL(agg1_kernel,  gA, blk, 0, stream, bufA, row_ptr, pk, dinv, b1, W2, bufB, n);
    hipLaunchKernelGGL(agg2_kernel,  gA, blk, 0, stream, bufB, row_ptr, pk, dinv, b2, Wl, bl, (float*)d_out, n);
}